// Round 3
// baseline (797.545 us; speedup 1.0000x reference)
//
#include <hip/hip_runtime.h>
#include <cstddef>
#include <cstdint>

#define T_LEN 512
#define O_DIM 4

typedef _Float16 f16x8 __attribute__((ext_vector_type(8)));
typedef float    f32x4 __attribute__((ext_vector_type(4)));

#define MFMA(a, b, c) __builtin_amdgcn_mfma_f32_16x16x32_f16((a), (b), (c), 0, 0, 0)

__device__ __forceinline__ float sigm_f(float x) {
    return __builtin_amdgcn_rcpf(1.0f + __builtin_amdgcn_exp2f(x * -1.44269504f));
}
__device__ __forceinline__ float tanh_f(float x) {
    float e = __builtin_amdgcn_exp2f(x * 2.88539008f);
    return __builtin_fmaf(-2.0f, __builtin_amdgcn_rcpf(e + 1.0f), 1.0f);
}

// B-fragment for 16x16x32 f16 MFMA from a row-major [K x 64] fp32 matrix.
__device__ __forceinline__ f16x8 load_bt(const float* __restrict__ W, int k0, int n) {
    const int lane = threadIdx.x & 63;
    const float* p = W + (size_t)(k0 + ((lane >> 4) << 3)) * 64 + n;
    f16x8 r;
#pragma unroll
    for (int j = 0; j < 8; ++j) r[j] = (_Float16)p[(size_t)j * 64];
    return r;
}

// A-fragment from LDS state array [16][72] f16.
__device__ __forceinline__ f16x8 ld_af(const _Float16* base, int kt) {
    const int lane = threadIdx.x & 63;
    const int m = lane & 15, q = lane >> 4;
    return *(const f16x8*)(base + m * 72 + kt * 32 + q * 8);
}

// 2 batch rows per block, 512 blocks -> 2 co-resident blocks per CU.
// R2 post-mortem: __launch_bounds__(256,2) capped VGPR at 128 (kernel needs
// ~190 for 40 resident weight fragments) -> scratch spills (WRITE_SIZE 8->55MB)
// on the serial chain -> 590us. THIS round keeps the (256,1) bound: compiler
// allocates ~192 VGPR naturally (no spill), and 192 <= 256 still permits
// 2 waves/SIMD, so the hardware co-schedules 2 independent blocks per CU
// whose latency/barrier stalls interleave (proven by R2's 21% occupancy).
// Scheduling discipline per segment (unchanged from the tuned baseline):
//   - EARLY fillers (operands from a PREVIOUS segment's read) cover this
//     segment's ds_read latency,
//   - critical MFMAs chain only onto accumulators whose last write completed
//     >=1 barrier earlier,
//   - LATE fillers issue after the critical publish and grind through the
//     barrier into the NEXT segment's read window.
// Retained: batched phi via Ahist; 64-step uniform x prefetch; 64-step
// buffered action flush.
__global__ __launch_bounds__(256, 1) void ANIMAZeroExact_86887188398421_kernel(
    const float* __restrict__ x,
    const float* __restrict__ Wenc_w, const float* __restrict__ Wenc_b,
    const float* __restrict__ WfW, const float* __restrict__ WfI, const float* __restrict__ WfA,
    const float* __restrict__ Wg_w, const float* __restrict__ Wg_b,
    const float* __restrict__ Iz_w, const float* __restrict__ Iz_b,
    const float* __restrict__ Ir_w, const float* __restrict__ Ir_b,
    const float* __restrict__ Ih_w, const float* __restrict__ Ih_b,
    const float* __restrict__ AfW, const float* __restrict__ AfI, const float* __restrict__ AfA,
    const float* __restrict__ Ag_w, const float* __restrict__ Ag_b,
    const float* __restrict__ phi_w, const float* __restrict__ phi_b,
    float* __restrict__ out)
{
    __shared__ __align__(16) _Float16 Wl[16][72];
    __shared__ __align__(16) _Float16 Il[16][72];
    __shared__ __align__(16) _Float16 Al[16][72];
    __shared__ __align__(16) _Float16 Rl[16][72];
    __shared__ __align__(16) _Float16 Ahist[16][4][72];  // [t&15][tilerow][dim] (rows 2,3 dup)
    __shared__ __align__(16) float xbig[2][520];         // 64-step x chunk, padded stride
    __shared__ __align__(16) float actb[2][64][4];       // 64-step action buffer

    const int tid  = threadIdx.x;
    const int w    = tid >> 6;
    const int lane = tid & 63;
    const int q    = lane >> 4;
    const int qb   = q & 1;          // real batch row this lane mirrors
    const int c    = lane & 15;
    const int n    = w * 16 + c;
    const int r0   = blockIdx.x * 2;

    // loop-invariant x-prefetch / flush lane mapping (one float4 per thread)
    const int prow = tid >> 7;           // 0..1
    const int pidx = tid & 127;
    const int psu  = pidx >> 1;          // 0..63 slot
    const int phl  = (pidx & 1) * 4;     // float4 half offset
    const int frow = tid >> 6;           // flush row (valid < 2)
    const int fs   = tid & 63;           // flush slot

    for (int i = tid; i < 16 * 72; i += 256) {
        (&Wl[0][0])[i] = (_Float16)0.0f; (&Il[0][0])[i] = (_Float16)0.0f;
        (&Al[0][0])[i] = (_Float16)0.0f; (&Rl[0][0])[i] = (_Float16)0.0f;
    }

    // ---- resident weight B-fragments ----
    f16x8 S1B[6], G1B[4], ZB[6], RB[6], HB[6], AB[6], AGB[4], phiB[2];
#pragma unroll
    for (int j = 0; j < 2; ++j) {
        S1B[j] = load_bt(WfW, 32 * j, n);  S1B[2 + j] = load_bt(WfI, 32 * j, n);  S1B[4 + j] = load_bt(WfA, 32 * j, n);
        AB[j]  = load_bt(AfW, 32 * j, n);  AB[2 + j]  = load_bt(AfI, 32 * j, n);  AB[4 + j]  = load_bt(AfA, 32 * j, n);
    }
#pragma unroll
    for (int j = 0; j < 4; ++j) { G1B[j] = load_bt(Wg_w, 32 * j, n); AGB[j] = load_bt(Ag_w, 32 * j, n); }
#pragma unroll
    for (int j = 0; j < 6; ++j) { ZB[j] = load_bt(Iz_w, 32 * j, n); RB[j] = load_bt(Ir_w, 32 * j, n); HB[j] = load_bt(Ih_w, 32 * j, n); }
    // phi fragment in ALL waves (batched phi); cols >= O_DIM zeroed
#pragma unroll
    for (int kt = 0; kt < 2; ++kt)
#pragma unroll
        for (int j = 0; j < 8; ++j) {
            int k = kt * 32 + q * 8 + j;
            phiB[kt][j] = (c < O_DIM) ? (_Float16)phi_w[k * O_DIM + c] : (_Float16)0.0f;
        }

    float We[8];
#pragma unroll
    for (int j = 0; j < 8; ++j) We[j] = Wenc_w[j * 64 + n];

    const float bias_g  = Wg_b[n],  bias_z = Iz_b[n], bias_r = Ir_b[n];
    const float bias_h  = Ih_b[n],  bias_ag = Ag_b[n], bias_e = Wenc_b[n];
    const float bias_p  = (c < O_DIM) ? phi_b[c] : 0.0f;

    f32x4 zero4 = {0.f, 0.f, 0.f, 0.f};

    // prologue: stage x-chunk slots 0..63 = x(1..64), one float4 per thread
    {
        const float* xg = x + (size_t)(r0 + prow) * (T_LEN * 8) + (1 + psu) * 8 + phl;
        *(float4*)(&xbig[prow][psu * 8 + phl]) = *(const float4*)(xg);
    }
    float xt;
    {
        const float* xg = x + (size_t)(r0 + qb) * (T_LEN * 8);
        float4 a = *(const float4*)(xg);
        float4 b = *(const float4*)(xg + 4);
        float d = bias_e;
        d = __builtin_fmaf(a.x, We[0], d); d = __builtin_fmaf(a.y, We[1], d);
        d = __builtin_fmaf(a.z, We[2], d); d = __builtin_fmaf(a.w, We[3], d);
        d = __builtin_fmaf(b.x, We[4], d); d = __builtin_fmaf(b.y, We[5], d);
        d = __builtin_fmaf(b.z, We[6], d); d = __builtin_fmaf(b.w, We[7], d);
        xt = tanh_f(d);
    }

    // loop-carried accumulators (all zero-init = value for states(-1)=0)
    f32x4 w_a = zero4, w_b = zero4, g_a = zero4, g_b = zero4;
    f32x4 zp_a = zero4, zp_c = zero4, rp_a = zero4, rp_c = zero4;
    f32x4 hp_a, hp_c, ap_a, ap_c, ag_a, ag_c;
    float Iv = 0.f;
    f16x8 nW0, nW1;

    __syncthreads();

#pragma unroll 1
    for (int t = 0; t < T_LEN; ++t) {
        const bool fl16 = ((t & 15) == 0) && (t > 0);
        const bool fl64 = ((t & 63) == 0) && (t > 0);

        // ============ seg1: W_new ============
        // read window covered by prev seg4's late fillers still in the pipe
        f16x8 sA0 = ld_af(&Al[0][0], 0), sA1 = ld_af(&Al[0][0], 1);
        float4 xra = {0,0,0,0};
        if (fl64) {  // uniform 64-step x prefetch (one float4 per thread)
            int off = (t + 1 + psu) * 8;
            if (off > T_LEN * 8 - 8) off = T_LEN * 8 - 8;
            xra = *(const float4*)(x + (size_t)(r0 + prow) * (T_LEN * 8) + off + phl);
        }
        // critical: w/g accumulators last touched in prev seg4-late (1 barrier ago)
        w_a = MFMA(sA0, S1B[4], w_a);  w_b = MFMA(sA1, S1B[5], w_b);
        g_a = MFMA(sA0, G1B[2], g_a);  g_b = MFMA(sA1, G1B[3], g_b);
        {
            float wn = tanh_f(xt + w_a[0] + w_b[0]) * sigm_f(g_a[0] + g_b[0] + bias_g);
            Wl[4 * q][n] = (_Float16)wn;
        }
        // late fillers: z/r A-terms (r's A-term must be 1 barrier before seg2's critical r)
        zp_a = MFMA(sA0, ZB[4], zp_a);  zp_c = MFMA(sA1, ZB[5], zp_c);
        rp_a = MFMA(sA0, RB[4], rp_a);  rp_c = MFMA(sA1, RB[5], rp_c);
        __syncthreads();  // alpha

        // ============ seg2: r*I ============
        nW0 = ld_af(&Wl[0][0], 0); nW1 = ld_af(&Wl[0][0], 1);
        // early fillers (sA-based, fresh accumulators) cover the nW read
        hp_a = MFMA(sA0, HB[4], zero4); hp_c = MFMA(sA1, HB[5], zero4);
        ap_a = MFMA(sA0, AB[4], zero4); ap_c = MFMA(sA1, AB[5], zero4);
        if (fl16) {
            // batched phi: actions for steps t-16..t-1 from Ahist, ALL waves,
            // wave w covers sub-steps 4w..4w+3. Fragment rows m -> (su=4w+(m>>2),
            // tilerow=m&3); bitwise-identical dot to the per-step scheme.
            const _Float16* ah = &Ahist[0][0][0];
            const int hw = (4 * w + (c >> 2)) * 288 + (c & 3) * 72 + 8 * q;
            f16x8 a0 = *(const f16x8*)(ah + hw);
            f16x8 a1 = *(const f16x8*)(ah + hw + 32);
            f32x4 act = MFMA(a0, phiB[0], zero4);
            act = MFMA(a1, phiB[1], act);
            if (c < O_DIM) {
                const int slot = (t - 16 + 4 * w + q) & 63;
#pragma unroll
                for (int rg = 0; rg < 2; ++rg)
                    actb[rg][slot][c] = act[rg] + bias_p;
            }
        }
        // critical: rp last touched seg1-late (1 barrier ago)
        rp_a = MFMA(nW0, RB[0], rp_a);  rp_c = MFMA(nW1, RB[1], rp_c);
        {
            float rv = sigm_f(rp_a[0] + rp_c[0] + bias_r);
            Rl[4 * q][n] = (_Float16)(rv * Iv);
        }
        // late fillers (nW-based): grind through beta into seg3's read window
        zp_a = MFMA(nW0, ZB[0], zp_a);  zp_c = MFMA(nW1, ZB[1], zp_c);
        hp_a = MFMA(nW0, HB[0], hp_a);  hp_c = MFMA(nW1, HB[1], hp_c);
        w_a  = MFMA(nW0, S1B[0], zero4); w_b = MFMA(nW1, S1B[1], zero4);
        if (fl64)
            *(float4*)(&xbig[prow][psu * 8 + phl]) = xra;
        __syncthreads();  // beta

        // ============ seg3: I_new ============
        f16x8 hR0 = ld_af(&Rl[0][0], 0), hR1 = ld_af(&Rl[0][0], 1);
        const float* xs = &xbig[qb][(t & 63) * 8];
        float4 qa = *(const float4*)xs;
        float4 qb4 = *(const float4*)(xs + 4);
        // early fillers (nW-based) + VALU cover the hR read
        ap_a = MFMA(nW0, AB[0], ap_a);  ap_c = MFMA(nW1, AB[1], ap_c);
        float zv = sigm_f(zp_a[0] + zp_c[0] + bias_z);
        float xtn;
        {
            float d = bias_e;
            d = __builtin_fmaf(qa.x, We[0], d); d = __builtin_fmaf(qa.y, We[1], d);
            d = __builtin_fmaf(qa.z, We[2], d); d = __builtin_fmaf(qa.w, We[3], d);
            d = __builtin_fmaf(qb4.x, We[4], d); d = __builtin_fmaf(qb4.y, We[5], d);
            d = __builtin_fmaf(qb4.z, We[6], d); d = __builtin_fmaf(qb4.w, We[7], d);
            xtn = tanh_f(d);
        }
        if (fl64 && tid < 128) {  // 64-step action flush (rows 0..1)
            float4 av = *(const float4*)(&actb[frow][fs][0]);
            *(float4*)(out + (size_t)(r0 + frow) * (T_LEN * O_DIM) + (t - 64 + fs) * 4) = av;
        }
        // critical: hp last touched seg2-late (1 barrier ago)
        hp_a = MFMA(hR0, HB[2], hp_a);  hp_c = MFMA(hR1, HB[3], hp_c);
        {
            float hv = tanh_f(hp_a[0] + hp_c[0] + bias_h);
            Iv = __builtin_fmaf(zv, hv - Iv, Iv);
            Il[4 * q][n] = (_Float16)Iv;
        }
        // late fillers (nW-based, fresh): grind through gamma into seg4's read window
        ag_a = MFMA(nW0, AGB[0], zero4); ag_c = MFMA(nW1, AGB[1], zero4);
        __syncthreads();  // gamma

        // ============ seg4: A_new ============
        f16x8 nI0 = ld_af(&Il[0][0], 0), nI1 = ld_af(&Il[0][0], 1);
        // critical: ap last touched seg3-early, ag seg3-late (completed by now)
        ap_a = MFMA(nI0, AB[2], ap_a);  ap_c = MFMA(nI1, AB[3], ap_c);
        ag_a = MFMA(nI0, AGB[2], ag_a); ag_c = MFMA(nI1, AGB[3], ag_c);
        {
            float av = tanh_f(ap_a[0] + ap_c[0]) * sigm_f(ag_a[0] + ag_c[0] + bias_ag);
            Al[4 * q][n] = (_Float16)av;
            Ahist[t & 15][q][n] = (_Float16)av;   // append to phi history (same cvt)
        }
        // late fillers (nI-based): next step's W/Wg/z/r I-terms; grind through delta
        // into seg1's read window
        w_a = MFMA(nI0, S1B[2], w_a);   w_b = MFMA(nI1, S1B[3], w_b);
        g_a = MFMA(nI0, G1B[0], zero4); g_b = MFMA(nI1, G1B[1], zero4);
        zp_a = MFMA(nI0, ZB[2], zero4); zp_c = MFMA(nI1, ZB[3], zero4);
        rp_a = MFMA(nI0, RB[2], zero4); rp_c = MFMA(nI1, RB[3], zero4);
        xt = xtn;
        __syncthreads();  // delta
    }

    // epilogue: final phi batch (steps 496..511) + final flush (448..511)
    {
        const _Float16* ah = &Ahist[0][0][0];
        const int hw = (4 * w + (c >> 2)) * 288 + (c & 3) * 72 + 8 * q;
        f16x8 a0 = *(const f16x8*)(ah + hw);
        f16x8 a1 = *(const f16x8*)(ah + hw + 32);
        f32x4 act = MFMA(a0, phiB[0], zero4);
        act = MFMA(a1, phiB[1], act);
        if (c < O_DIM) {
            const int slot = 48 + 4 * w + q;   // (512-16+4w+q)&63
#pragma unroll
            for (int rg = 0; rg < 2; ++rg)
                actb[rg][slot][c] = act[rg] + bias_p;
        }
        __syncthreads();
        if (tid < 128) {
            float4 av = *(const float4*)(&actb[frow][fs][0]);
            *(float4*)(out + (size_t)(r0 + frow) * (T_LEN * O_DIM) + (448 + fs) * 4) = av;
        }
    }
}

extern "C" void kernel_launch(void* const* d_in, const int* in_sizes, int n_in,
                              void* d_out, int out_size, void* d_ws, size_t ws_size,
                              hipStream_t stream) {
    ANIMAZeroExact_86887188398421_kernel<<<dim3(512), dim3(256), 0, stream>>>(
        (const float*)d_in[0],
        (const float*)d_in[1],  (const float*)d_in[2],
        (const float*)d_in[3],  (const float*)d_in[4],  (const float*)d_in[5],
        (const float*)d_in[6],  (const float*)d_in[7],
        (const float*)d_in[8],  (const float*)d_in[9],
        (const float*)d_in[10], (const float*)d_in[11],
        (const float*)d_in[12], (const float*)d_in[13],
        (const float*)d_in[14], (const float*)d_in[15], (const float*)d_in[16],
        (const float*)d_in[17], (const float*)d_in[18],
        (const float*)d_in[19], (const float*)d_in[20],
        (float*)d_out);
}

// Round 4
// 710.792 us; speedup vs baseline: 1.1221x; 1.1221x over previous
//
#include <hip/hip_runtime.h>
#include <cstddef>
#include <cstdint>

#define T_LEN 512
#define O_DIM 4

typedef _Float16 f16x8 __attribute__((ext_vector_type(8)));
typedef float    f32x4 __attribute__((ext_vector_type(4)));

#define MFMA(a, b, c) __builtin_amdgcn_mfma_f32_16x16x32_f16((a), (b), (c), 0, 0, 0)

__device__ __forceinline__ float sigm_f(float x) {
    return __builtin_amdgcn_rcpf(1.0f + __builtin_amdgcn_exp2f(x * -1.44269504f));
}
__device__ __forceinline__ float tanh_f(float x) {
    float e = __builtin_amdgcn_exp2f(x * 2.88539008f);
    return __builtin_fmaf(-2.0f, __builtin_amdgcn_rcpf(e + 1.0f), 1.0f);
}

// B-fragment for 16x16x32 f16 MFMA from a row-major [K x 64] fp32 matrix.
__device__ __forceinline__ f16x8 load_bt(const float* __restrict__ W, int k0, int n) {
    const int lane = threadIdx.x & 63;
    const float* p = W + (size_t)(k0 + ((lane >> 4) << 3)) * 64 + n;
    f16x8 r;
#pragma unroll
    for (int j = 0; j < 8; ++j) r[j] = (_Float16)p[(size_t)j * 64];
    return r;
}

// A-fragment from LDS state array [16][72] f16.
__device__ __forceinline__ f16x8 ld_af(const _Float16* base, int kt) {
    const int lane = threadIdx.x & 63;
    const int m = lane & 15, q = lane >> 4;
    return *(const f16x8*)(base + m * 72 + kt * 32 + q * 8);
}

// R3 post-mortem: unified VGPR+AGPR file -> total regs >256/wave -> pinned at
// 1 wave/SIMD; cross-block co-residency unreachable with resident weights.
// THIS round: fill latency bubbles WITHIN the wave. Each block runs TWO
// independent recurrence chains (A = rows r0..r0+1, B = rows r0+2..r0+3,
// 2 valid rows each via the proven q&1 mirror), sharing resident weights.
// Within each barrier segment the chains interleave: A's ds_read/MFMA/trans
// latency is covered by B's independent issue and vice versa. At 1 wave/SIMD
// the extra ~80 regs for chain B cost no occupancy (budget 512/wave).
__global__ __launch_bounds__(256, 1) void ANIMAZeroExact_86887188398421_kernel(
    const float* __restrict__ x,
    const float* __restrict__ Wenc_w, const float* __restrict__ Wenc_b,
    const float* __restrict__ WfW, const float* __restrict__ WfI, const float* __restrict__ WfA,
    const float* __restrict__ Wg_w, const float* __restrict__ Wg_b,
    const float* __restrict__ Iz_w, const float* __restrict__ Iz_b,
    const float* __restrict__ Ir_w, const float* __restrict__ Ir_b,
    const float* __restrict__ Ih_w, const float* __restrict__ Ih_b,
    const float* __restrict__ AfW, const float* __restrict__ AfI, const float* __restrict__ AfA,
    const float* __restrict__ Ag_w, const float* __restrict__ Ag_b,
    const float* __restrict__ phi_w, const float* __restrict__ phi_b,
    float* __restrict__ out)
{
    __shared__ __align__(16) _Float16 WlA[16][72], IlA[16][72], AlA[16][72], RlA[16][72];
    __shared__ __align__(16) _Float16 WlB[16][72], IlB[16][72], AlB[16][72], RlB[16][72];
    __shared__ __align__(16) _Float16 AhistA[16][4][72], AhistB[16][4][72];
    __shared__ __align__(16) float xbig[4][520];     // 64-step x chunk, 4 rows
    __shared__ __align__(16) float actb[4][64][4];   // 64-step action buffer, 4 rows

    const int tid  = threadIdx.x;
    const int w    = tid >> 6;
    const int lane = tid & 63;
    const int q    = lane >> 4;
    const int qb   = q & 1;
    const int c    = lane & 15;
    const int n    = w * 16 + c;
    const int r0   = blockIdx.x * 4;

    const int prow = tid >> 6;       // x prefetch: 4 rows x 64 slots, 2 float4/thread
    const int psu  = tid & 63;
    const int frow = tid >> 6;       // flush: 4 rows x 64 slots
    const int fs   = tid & 63;

    for (int i = tid; i < 16 * 72; i += 256) {
        (&WlA[0][0])[i] = (_Float16)0.0f; (&IlA[0][0])[i] = (_Float16)0.0f;
        (&AlA[0][0])[i] = (_Float16)0.0f; (&RlA[0][0])[i] = (_Float16)0.0f;
        (&WlB[0][0])[i] = (_Float16)0.0f; (&IlB[0][0])[i] = (_Float16)0.0f;
        (&AlB[0][0])[i] = (_Float16)0.0f; (&RlB[0][0])[i] = (_Float16)0.0f;
    }

    // ---- resident weight B-fragments (shared by both chains) ----
    f16x8 S1B[6], G1B[4], ZB[6], RB[6], HB[6], AB[6], AGB[4], phiB[2];
#pragma unroll
    for (int j = 0; j < 2; ++j) {
        S1B[j] = load_bt(WfW, 32 * j, n);  S1B[2 + j] = load_bt(WfI, 32 * j, n);  S1B[4 + j] = load_bt(WfA, 32 * j, n);
        AB[j]  = load_bt(AfW, 32 * j, n);  AB[2 + j]  = load_bt(AfI, 32 * j, n);  AB[4 + j]  = load_bt(AfA, 32 * j, n);
    }
#pragma unroll
    for (int j = 0; j < 4; ++j) { G1B[j] = load_bt(Wg_w, 32 * j, n); AGB[j] = load_bt(Ag_w, 32 * j, n); }
#pragma unroll
    for (int j = 0; j < 6; ++j) { ZB[j] = load_bt(Iz_w, 32 * j, n); RB[j] = load_bt(Ir_w, 32 * j, n); HB[j] = load_bt(Ih_w, 32 * j, n); }
#pragma unroll
    for (int kt = 0; kt < 2; ++kt)
#pragma unroll
        for (int j = 0; j < 8; ++j) {
            int k = kt * 32 + q * 8 + j;
            phiB[kt][j] = (c < O_DIM) ? (_Float16)phi_w[k * O_DIM + c] : (_Float16)0.0f;
        }

    float We[8];
#pragma unroll
    for (int j = 0; j < 8; ++j) We[j] = Wenc_w[j * 64 + n];

    const float bias_g  = Wg_b[n],  bias_z = Iz_b[n], bias_r = Ir_b[n];
    const float bias_h  = Ih_b[n],  bias_ag = Ag_b[n], bias_e = Wenc_b[n];
    const float bias_p  = (c < O_DIM) ? phi_b[c] : 0.0f;

    f32x4 zero4 = {0.f, 0.f, 0.f, 0.f};

    // prologue: stage x-chunk slots 0..63 = x(1..64), 4 rows
    {
        const float* xg = x + (size_t)(r0 + prow) * (T_LEN * 8) + (1 + psu) * 8;
        float4 a = *(const float4*)(xg);
        float4 b = *(const float4*)(xg + 4);
        float* d = &xbig[prow][psu * 8];
        *(float4*)d = a; *(float4*)(d + 4) = b;
    }
    float xtA, xtB;
    {
        const float* xg = x + (size_t)(r0 + qb) * (T_LEN * 8);
        float4 a = *(const float4*)(xg);
        float4 b = *(const float4*)(xg + 4);
        float d = bias_e;
        d = __builtin_fmaf(a.x, We[0], d); d = __builtin_fmaf(a.y, We[1], d);
        d = __builtin_fmaf(a.z, We[2], d); d = __builtin_fmaf(a.w, We[3], d);
        d = __builtin_fmaf(b.x, We[4], d); d = __builtin_fmaf(b.y, We[5], d);
        d = __builtin_fmaf(b.z, We[6], d); d = __builtin_fmaf(b.w, We[7], d);
        xtA = tanh_f(d);
    }
    {
        const float* xg = x + (size_t)(r0 + 2 + qb) * (T_LEN * 8);
        float4 a = *(const float4*)(xg);
        float4 b = *(const float4*)(xg + 4);
        float d = bias_e;
        d = __builtin_fmaf(a.x, We[0], d); d = __builtin_fmaf(a.y, We[1], d);
        d = __builtin_fmaf(a.z, We[2], d); d = __builtin_fmaf(a.w, We[3], d);
        d = __builtin_fmaf(b.x, We[4], d); d = __builtin_fmaf(b.y, We[5], d);
        d = __builtin_fmaf(b.z, We[6], d); d = __builtin_fmaf(b.w, We[7], d);
        xtB = tanh_f(d);
    }

    f32x4 w_aA = zero4, w_bA = zero4, g_aA = zero4, g_bA = zero4;
    f32x4 zp_aA = zero4, zp_cA = zero4, rp_aA = zero4, rp_cA = zero4;
    f32x4 hp_aA, hp_cA, ap_aA, ap_cA, ag_aA, ag_cA;
    f32x4 w_aB = zero4, w_bB = zero4, g_aB = zero4, g_bB = zero4;
    f32x4 zp_aB = zero4, zp_cB = zero4, rp_aB = zero4, rp_cB = zero4;
    f32x4 hp_aB, hp_cB, ap_aB, ap_cB, ag_aB, ag_cB;
    float IvA = 0.f, IvB = 0.f;
    f16x8 nW0A, nW1A, nW0B, nW1B;

    __syncthreads();

#pragma unroll 1
    for (int t = 0; t < T_LEN; ++t) {
        const bool fl16 = ((t & 15) == 0) && (t > 0);
        const bool fl64 = ((t & 63) == 0) && (t > 0);

        // ============ seg1: W_new (both chains) ============
        f16x8 sA0A = ld_af(&AlA[0][0], 0), sA1A = ld_af(&AlA[0][0], 1);
        f16x8 sA0B = ld_af(&AlB[0][0], 0), sA1B = ld_af(&AlB[0][0], 1);
        float4 xra = {0,0,0,0}, xrb = {0,0,0,0};
        if (fl64) {
            int off = (t + 1 + psu) * 8;
            if (off > T_LEN * 8 - 8) off = T_LEN * 8 - 8;
            const float* xg = x + (size_t)(r0 + prow) * (T_LEN * 8) + off;
            xra = *(const float4*)(xg); xrb = *(const float4*)(xg + 4);
        }
        w_aA = MFMA(sA0A, S1B[4], w_aA);  w_bA = MFMA(sA1A, S1B[5], w_bA);
        w_aB = MFMA(sA0B, S1B[4], w_aB);  w_bB = MFMA(sA1B, S1B[5], w_bB);
        g_aA = MFMA(sA0A, G1B[2], g_aA);  g_bA = MFMA(sA1A, G1B[3], g_bA);
        g_aB = MFMA(sA0B, G1B[2], g_aB);  g_bB = MFMA(sA1B, G1B[3], g_bB);
        {
            float wn = tanh_f(xtA + w_aA[0] + w_bA[0]) * sigm_f(g_aA[0] + g_bA[0] + bias_g);
            WlA[4 * q][n] = (_Float16)wn;
        }
        {
            float wn = tanh_f(xtB + w_aB[0] + w_bB[0]) * sigm_f(g_aB[0] + g_bB[0] + bias_g);
            WlB[4 * q][n] = (_Float16)wn;
        }
        zp_aA = MFMA(sA0A, ZB[4], zp_aA);  zp_cA = MFMA(sA1A, ZB[5], zp_cA);
        rp_aA = MFMA(sA0A, RB[4], rp_aA);  rp_cA = MFMA(sA1A, RB[5], rp_cA);
        zp_aB = MFMA(sA0B, ZB[4], zp_aB);  zp_cB = MFMA(sA1B, ZB[5], zp_cB);
        rp_aB = MFMA(sA0B, RB[4], rp_aB);  rp_cB = MFMA(sA1B, RB[5], rp_cB);
        __syncthreads();  // alpha

        // ============ seg2: r*I (both chains) ============
        nW0A = ld_af(&WlA[0][0], 0); nW1A = ld_af(&WlA[0][0], 1);
        nW0B = ld_af(&WlB[0][0], 0); nW1B = ld_af(&WlB[0][0], 1);
        hp_aA = MFMA(sA0A, HB[4], zero4); hp_cA = MFMA(sA1A, HB[5], zero4);
        hp_aB = MFMA(sA0B, HB[4], zero4); hp_cB = MFMA(sA1B, HB[5], zero4);
        ap_aA = MFMA(sA0A, AB[4], zero4); ap_cA = MFMA(sA1A, AB[5], zero4);
        ap_aB = MFMA(sA0B, AB[4], zero4); ap_cB = MFMA(sA1B, AB[5], zero4);
        if (fl16) {
            const int hw = (4 * w + (c >> 2)) * 288 + (c & 3) * 72 + 8 * q;
            const int slot = (t - 16 + 4 * w + q) & 63;
            {
                const _Float16* ah = &AhistA[0][0][0];
                f16x8 a0 = *(const f16x8*)(ah + hw);
                f16x8 a1 = *(const f16x8*)(ah + hw + 32);
                f32x4 act = MFMA(a0, phiB[0], zero4);
                act = MFMA(a1, phiB[1], act);
                if (c < O_DIM) {
#pragma unroll
                    for (int rg = 0; rg < 2; ++rg)
                        actb[rg][slot][c] = act[rg] + bias_p;
                }
            }
            {
                const _Float16* ah = &AhistB[0][0][0];
                f16x8 a0 = *(const f16x8*)(ah + hw);
                f16x8 a1 = *(const f16x8*)(ah + hw + 32);
                f32x4 act = MFMA(a0, phiB[0], zero4);
                act = MFMA(a1, phiB[1], act);
                if (c < O_DIM) {
#pragma unroll
                    for (int rg = 0; rg < 2; ++rg)
                        actb[2 + rg][slot][c] = act[rg] + bias_p;
                }
            }
        }
        rp_aA = MFMA(nW0A, RB[0], rp_aA);  rp_cA = MFMA(nW1A, RB[1], rp_cA);
        rp_aB = MFMA(nW0B, RB[0], rp_aB);  rp_cB = MFMA(nW1B, RB[1], rp_cB);
        {
            float rv = sigm_f(rp_aA[0] + rp_cA[0] + bias_r);
            RlA[4 * q][n] = (_Float16)(rv * IvA);
        }
        {
            float rv = sigm_f(rp_aB[0] + rp_cB[0] + bias_r);
            RlB[4 * q][n] = (_Float16)(rv * IvB);
        }
        zp_aA = MFMA(nW0A, ZB[0], zp_aA);  zp_cA = MFMA(nW1A, ZB[1], zp_cA);
        zp_aB = MFMA(nW0B, ZB[0], zp_aB);  zp_cB = MFMA(nW1B, ZB[1], zp_cB);
        hp_aA = MFMA(nW0A, HB[0], hp_aA);  hp_cA = MFMA(nW1A, HB[1], hp_cA);
        hp_aB = MFMA(nW0B, HB[0], hp_aB);  hp_cB = MFMA(nW1B, HB[1], hp_cB);
        w_aA  = MFMA(nW0A, S1B[0], zero4); w_bA = MFMA(nW1A, S1B[1], zero4);
        w_aB  = MFMA(nW0B, S1B[0], zero4); w_bB = MFMA(nW1B, S1B[1], zero4);
        if (fl64) {
            float* d = &xbig[prow][psu * 8];
            *(float4*)d = xra; *(float4*)(d + 4) = xrb;
        }
        __syncthreads();  // beta

        // ============ seg3: I_new (both chains) ============
        f16x8 hR0A = ld_af(&RlA[0][0], 0), hR1A = ld_af(&RlA[0][0], 1);
        f16x8 hR0B = ld_af(&RlB[0][0], 0), hR1B = ld_af(&RlB[0][0], 1);
        const float* xsA = &xbig[qb][(t & 63) * 8];
        const float* xsB = &xbig[2 + qb][(t & 63) * 8];
        float4 qaA = *(const float4*)xsA;
        float4 qbA = *(const float4*)(xsA + 4);
        float4 qaB = *(const float4*)xsB;
        float4 qbB = *(const float4*)(xsB + 4);
        ap_aA = MFMA(nW0A, AB[0], ap_aA);  ap_cA = MFMA(nW1A, AB[1], ap_cA);
        ap_aB = MFMA(nW0B, AB[0], ap_aB);  ap_cB = MFMA(nW1B, AB[1], ap_cB);
        float zvA = sigm_f(zp_aA[0] + zp_cA[0] + bias_z);
        float zvB = sigm_f(zp_aB[0] + zp_cB[0] + bias_z);
        float xtnA, xtnB;
        {
            float d = bias_e;
            d = __builtin_fmaf(qaA.x, We[0], d); d = __builtin_fmaf(qaA.y, We[1], d);
            d = __builtin_fmaf(qaA.z, We[2], d); d = __builtin_fmaf(qaA.w, We[3], d);
            d = __builtin_fmaf(qbA.x, We[4], d); d = __builtin_fmaf(qbA.y, We[5], d);
            d = __builtin_fmaf(qbA.z, We[6], d); d = __builtin_fmaf(qbA.w, We[7], d);
            xtnA = tanh_f(d);
        }
        {
            float d = bias_e;
            d = __builtin_fmaf(qaB.x, We[0], d); d = __builtin_fmaf(qaB.y, We[1], d);
            d = __builtin_fmaf(qaB.z, We[2], d); d = __builtin_fmaf(qaB.w, We[3], d);
            d = __builtin_fmaf(qbB.x, We[4], d); d = __builtin_fmaf(qbB.y, We[5], d);
            d = __builtin_fmaf(qbB.z, We[6], d); d = __builtin_fmaf(qbB.w, We[7], d);
            xtnB = tanh_f(d);
        }
        if (fl64) {
            float4 av = *(const float4*)(&actb[frow][fs][0]);
            *(float4*)(out + (size_t)(r0 + frow) * (T_LEN * O_DIM) + (t - 64 + fs) * 4) = av;
        }
        hp_aA = MFMA(hR0A, HB[2], hp_aA);  hp_cA = MFMA(hR1A, HB[3], hp_cA);
        hp_aB = MFMA(hR0B, HB[2], hp_aB);  hp_cB = MFMA(hR1B, HB[3], hp_cB);
        {
            float hv = tanh_f(hp_aA[0] + hp_cA[0] + bias_h);
            IvA = __builtin_fmaf(zvA, hv - IvA, IvA);
            IlA[4 * q][n] = (_Float16)IvA;
        }
        {
            float hv = tanh_f(hp_aB[0] + hp_cB[0] + bias_h);
            IvB = __builtin_fmaf(zvB, hv - IvB, IvB);
            IlB[4 * q][n] = (_Float16)IvB;
        }
        ag_aA = MFMA(nW0A, AGB[0], zero4); ag_cA = MFMA(nW1A, AGB[1], zero4);
        ag_aB = MFMA(nW0B, AGB[0], zero4); ag_cB = MFMA(nW1B, AGB[1], zero4);
        __syncthreads();  // gamma

        // ============ seg4: A_new (both chains) ============
        f16x8 nI0A = ld_af(&IlA[0][0], 0), nI1A = ld_af(&IlA[0][0], 1);
        f16x8 nI0B = ld_af(&IlB[0][0], 0), nI1B = ld_af(&IlB[0][0], 1);
        ap_aA = MFMA(nI0A, AB[2], ap_aA);  ap_cA = MFMA(nI1A, AB[3], ap_cA);
        ap_aB = MFMA(nI0B, AB[2], ap_aB);  ap_cB = MFMA(nI1B, AB[3], ap_cB);
        ag_aA = MFMA(nI0A, AGB[2], ag_aA); ag_cA = MFMA(nI1A, AGB[3], ag_cA);
        ag_aB = MFMA(nI0B, AGB[2], ag_aB); ag_cB = MFMA(nI1B, AGB[3], ag_cB);
        {
            float av = tanh_f(ap_aA[0] + ap_cA[0]) * sigm_f(ag_aA[0] + ag_cA[0] + bias_ag);
            AlA[4 * q][n] = (_Float16)av;
            AhistA[t & 15][q][n] = (_Float16)av;
        }
        {
            float av = tanh_f(ap_aB[0] + ap_cB[0]) * sigm_f(ag_aB[0] + ag_cB[0] + bias_ag);
            AlB[4 * q][n] = (_Float16)av;
            AhistB[t & 15][q][n] = (_Float16)av;
        }
        w_aA = MFMA(nI0A, S1B[2], w_aA);   w_bA = MFMA(nI1A, S1B[3], w_bA);
        w_aB = MFMA(nI0B, S1B[2], w_aB);   w_bB = MFMA(nI1B, S1B[3], w_bB);
        g_aA = MFMA(nI0A, G1B[0], zero4);  g_bA = MFMA(nI1A, G1B[1], zero4);
        g_aB = MFMA(nI0B, G1B[0], zero4);  g_bB = MFMA(nI1B, G1B[1], zero4);
        zp_aA = MFMA(nI0A, ZB[2], zero4);  zp_cA = MFMA(nI1A, ZB[3], zero4);
        zp_aB = MFMA(nI0B, ZB[2], zero4);  zp_cB = MFMA(nI1B, ZB[3], zero4);
        rp_aA = MFMA(nI0A, RB[2], zero4);  rp_cA = MFMA(nI1A, RB[3], zero4);
        rp_aB = MFMA(nI0B, RB[2], zero4);  rp_cB = MFMA(nI1B, RB[3], zero4);
        xtA = xtnA; xtB = xtnB;
        __syncthreads();  // delta
    }

    // epilogue: final phi batch (steps 496..511) + final flush (448..511)
    {
        const int hw = (4 * w + (c >> 2)) * 288 + (c & 3) * 72 + 8 * q;
        const int slot = 48 + 4 * w + q;
        {
            const _Float16* ah = &AhistA[0][0][0];
            f16x8 a0 = *(const f16x8*)(ah + hw);
            f16x8 a1 = *(const f16x8*)(ah + hw + 32);
            f32x4 act = MFMA(a0, phiB[0], zero4);
            act = MFMA(a1, phiB[1], act);
            if (c < O_DIM) {
#pragma unroll
                for (int rg = 0; rg < 2; ++rg)
                    actb[rg][slot][c] = act[rg] + bias_p;
            }
        }
        {
            const _Float16* ah = &AhistB[0][0][0];
            f16x8 a0 = *(const f16x8*)(ah + hw);
            f16x8 a1 = *(const f16x8*)(ah + hw + 32);
            f32x4 act = MFMA(a0, phiB[0], zero4);
            act = MFMA(a1, phiB[1], act);
            if (c < O_DIM) {
#pragma unroll
                for (int rg = 0; rg < 2; ++rg)
                    actb[2 + rg][slot][c] = act[rg] + bias_p;
            }
        }
        __syncthreads();
        float4 av = *(const float4*)(&actb[frow][fs][0]);
        *(float4*)(out + (size_t)(r0 + frow) * (T_LEN * O_DIM) + (448 + fs) * 4) = av;
    }
}

extern "C" void kernel_launch(void* const* d_in, const int* in_sizes, int n_in,
                              void* d_out, int out_size, void* d_ws, size_t ws_size,
                              hipStream_t stream) {
    ANIMAZeroExact_86887188398421_kernel<<<dim3(256), dim3(256), 0, stream>>>(
        (const float*)d_in[0],
        (const float*)d_in[1],  (const float*)d_in[2],
        (const float*)d_in[3],  (const float*)d_in[4],  (const float*)d_in[5],
        (const float*)d_in[6],  (const float*)d_in[7],
        (const float*)d_in[8],  (const float*)d_in[9],
        (const float*)d_in[10], (const float*)d_in[11],
        (const float*)d_in[12], (const float*)d_in[13],
        (const float*)d_in[14], (const float*)d_in[15], (const float*)d_in[16],
        (const float*)d_in[17], (const float*)d_in[18],
        (const float*)d_in[19], (const float*)d_in[20],
        (float*)d_out);
}

// Round 5
// 457.315 us; speedup vs baseline: 1.7440x; 1.5543x over previous
//
#include <hip/hip_runtime.h>
#include <cstddef>
#include <cstdint>

#define T_LEN 512
#define O_DIM 4

typedef _Float16 f16x8 __attribute__((ext_vector_type(8)));
typedef _Float16 f16x4 __attribute__((ext_vector_type(4)));
typedef float    f32x4 __attribute__((ext_vector_type(4)));

#define MFMA(a, b, c) __builtin_amdgcn_mfma_f32_16x16x32_f16((a), (b), (c), 0, 0, 0)

__device__ __forceinline__ float sigm_f(float x) {
    return __builtin_amdgcn_rcpf(1.0f + __builtin_amdgcn_exp2f(x * -1.44269504f));
}
__device__ __forceinline__ float tanh_f(float x) {
    float e = __builtin_amdgcn_exp2f(x * 2.88539008f);
    return __builtin_fmaf(-2.0f, __builtin_amdgcn_rcpf(e + 1.0f), 1.0f);
}

// B-fragment for 16x16x32 f16 MFMA from a row-major [K x 64] fp32 matrix.
__device__ __forceinline__ f16x8 load_bt(const float* __restrict__ W, int k0, int n) {
    const int lane = threadIdx.x & 63;
    const float* p = W + (size_t)(k0 + ((lane >> 4) << 3)) * 64 + n;
    f16x8 r;
#pragma unroll
    for (int j = 0; j < 8; ++j) r[j] = (_Float16)p[(size_t)j * 64];
    return r;
}

// A-fragment from LDS state array [16][76] f16.
// Stride 76 f16 = 152 B = 19*8 B: 8B-aligned (so b64 reads), and the dword
// bank base (6m + 16kt + 4q + 2h) mod 32 spreads the 16 m-rows over 16
// DISTINCT banks (~2-way worst case, free per m136). The old [16][72]
// layout put every lane's b128 base on a bank = 0 mod 4 (8 groups for 64
// lanes, ~8-way) -- measured 1.7e7 conflict cycles = ~2.7 cy per LDS op.
__device__ __forceinline__ f16x8 ld_af(const _Float16* base, int kt) {
    const int lane = threadIdx.x & 63;
    const int m = lane & 15, q = lane >> 4;
    const _Float16* p = base + m * 76 + kt * 32 + q * 8;
    f16x4 lo = *(const f16x4*)(p);
    f16x4 hi = *(const f16x4*)(p + 4);
    f16x8 r;
    r[0] = lo[0]; r[1] = lo[1]; r[2] = lo[2]; r[3] = lo[3];
    r[4] = hi[0]; r[5] = hi[1]; r[6] = hi[2]; r[7] = hi[3];
    return r;
}

// 256 threads = 4 waves, 4 valid batch rows at tile rows {0,4,8,12}.
// (R4 post-mortem: dual-chain in-wave was strictly wasteful -- the 16-row
// MFMA tile already carries 4 rows for free. R3: co-residency unreachable
// (unified VGPR+AGPR > 256/wave). This round = R1 base + bank-conflict fix
// on the critical ld_af path.)
// Scheduling discipline per segment (unchanged from the tuned baseline):
//   - EARLY fillers (operands from a PREVIOUS segment's read) cover this
//     segment's ds_read latency,
//   - critical MFMAs chain only onto accumulators whose last write completed
//     >=1 barrier earlier,
//   - LATE fillers issue after the critical publish and grind through the
//     barrier into the NEXT segment's read window.
// Retained: batched phi via Ahist; 64-step uniform x prefetch; 64-step
// buffered action flush.
__global__ __launch_bounds__(256, 1) void ANIMAZeroExact_86887188398421_kernel(
    const float* __restrict__ x,
    const float* __restrict__ Wenc_w, const float* __restrict__ Wenc_b,
    const float* __restrict__ WfW, const float* __restrict__ WfI, const float* __restrict__ WfA,
    const float* __restrict__ Wg_w, const float* __restrict__ Wg_b,
    const float* __restrict__ Iz_w, const float* __restrict__ Iz_b,
    const float* __restrict__ Ir_w, const float* __restrict__ Ir_b,
    const float* __restrict__ Ih_w, const float* __restrict__ Ih_b,
    const float* __restrict__ AfW, const float* __restrict__ AfI, const float* __restrict__ AfA,
    const float* __restrict__ Ag_w, const float* __restrict__ Ag_b,
    const float* __restrict__ phi_w, const float* __restrict__ phi_b,
    float* __restrict__ out)
{
    __shared__ __align__(16) _Float16 Wl[16][76];
    __shared__ __align__(16) _Float16 Il[16][76];
    __shared__ __align__(16) _Float16 Al[16][76];
    __shared__ __align__(16) _Float16 Rl[16][76];
    __shared__ __align__(16) _Float16 Ahist[16][4][72];  // [t&15][rowidx][dim]; 16B-aligned rows, b128 ok (rare)
    __shared__ __align__(16) float xbig[4][520];         // 64-step x chunk, padded stride
    __shared__ __align__(16) float actb[4][64][4];       // 64-step action buffer

    const int tid  = threadIdx.x;
    const int w    = tid >> 6;
    const int lane = tid & 63;
    const int q    = lane >> 4;
    const int c    = lane & 15;
    const int n    = w * 16 + c;
    const int r0   = blockIdx.x * 4;

    const int prow = tid >> 6;       // x prefetch: 4 rows x 64 slots, 2 float4/thread
    const int psu  = tid & 63;
    const int frow = tid >> 6;       // flush: 4 rows x 64 slots
    const int fs   = tid & 63;

    for (int i = tid; i < 16 * 76; i += 256) {
        (&Wl[0][0])[i] = (_Float16)0.0f; (&Il[0][0])[i] = (_Float16)0.0f;
        (&Al[0][0])[i] = (_Float16)0.0f; (&Rl[0][0])[i] = (_Float16)0.0f;
    }

    // ---- resident weight B-fragments ----
    f16x8 S1B[6], G1B[4], ZB[6], RB[6], HB[6], AB[6], AGB[4], phiB[2];
#pragma unroll
    for (int j = 0; j < 2; ++j) {
        S1B[j] = load_bt(WfW, 32 * j, n);  S1B[2 + j] = load_bt(WfI, 32 * j, n);  S1B[4 + j] = load_bt(WfA, 32 * j, n);
        AB[j]  = load_bt(AfW, 32 * j, n);  AB[2 + j]  = load_bt(AfI, 32 * j, n);  AB[4 + j]  = load_bt(AfA, 32 * j, n);
    }
#pragma unroll
    for (int j = 0; j < 4; ++j) { G1B[j] = load_bt(Wg_w, 32 * j, n); AGB[j] = load_bt(Ag_w, 32 * j, n); }
#pragma unroll
    for (int j = 0; j < 6; ++j) { ZB[j] = load_bt(Iz_w, 32 * j, n); RB[j] = load_bt(Ir_w, 32 * j, n); HB[j] = load_bt(Ih_w, 32 * j, n); }
    // phi fragment in ALL waves (batched phi); cols >= O_DIM zeroed
#pragma unroll
    for (int kt = 0; kt < 2; ++kt)
#pragma unroll
        for (int j = 0; j < 8; ++j) {
            int k = kt * 32 + q * 8 + j;
            phiB[kt][j] = (c < O_DIM) ? (_Float16)phi_w[k * O_DIM + c] : (_Float16)0.0f;
        }

    float We[8];
#pragma unroll
    for (int j = 0; j < 8; ++j) We[j] = Wenc_w[j * 64 + n];

    const float bias_g  = Wg_b[n],  bias_z = Iz_b[n], bias_r = Ir_b[n];
    const float bias_h  = Ih_b[n],  bias_ag = Ag_b[n], bias_e = Wenc_b[n];
    const float bias_p  = (c < O_DIM) ? phi_b[c] : 0.0f;

    f32x4 zero4 = {0.f, 0.f, 0.f, 0.f};

    // prologue: stage x-chunk slots 0..63 = x(1..64), all threads uniform
    {
        const float* xg = x + (size_t)(r0 + prow) * (T_LEN * 8) + (1 + psu) * 8;
        float4 a = *(const float4*)(xg);
        float4 b = *(const float4*)(xg + 4);
        float* d = &xbig[prow][psu * 8];
        *(float4*)d = a; *(float4*)(d + 4) = b;
    }
    float xt;
    {
        const float* xg = x + (size_t)(r0 + q) * (T_LEN * 8);
        float4 a = *(const float4*)(xg);
        float4 b = *(const float4*)(xg + 4);
        float d = bias_e;
        d = __builtin_fmaf(a.x, We[0], d); d = __builtin_fmaf(a.y, We[1], d);
        d = __builtin_fmaf(a.z, We[2], d); d = __builtin_fmaf(a.w, We[3], d);
        d = __builtin_fmaf(b.x, We[4], d); d = __builtin_fmaf(b.y, We[5], d);
        d = __builtin_fmaf(b.z, We[6], d); d = __builtin_fmaf(b.w, We[7], d);
        xt = tanh_f(d);
    }

    // loop-carried accumulators (all zero-init = value for states(-1)=0)
    f32x4 w_a = zero4, w_b = zero4, g_a = zero4, g_b = zero4;
    f32x4 zp_a = zero4, zp_c = zero4, rp_a = zero4, rp_c = zero4;
    f32x4 hp_a, hp_c, ap_a, ap_c, ag_a, ag_c;
    float Iv = 0.f;
    f16x8 nW0, nW1;

    __syncthreads();

#pragma unroll 1
    for (int t = 0; t < T_LEN; ++t) {
        const bool fl16 = ((t & 15) == 0) && (t > 0);
        const bool fl64 = ((t & 63) == 0) && (t > 0);

        // ============ seg1: W_new ============
        // read window covered by prev seg4's late fillers still in the pipe
        f16x8 sA0 = ld_af(&Al[0][0], 0), sA1 = ld_af(&Al[0][0], 1);
        float4 xra = {0,0,0,0}, xrb = {0,0,0,0};
        if (fl64) {  // uniform 64-step x prefetch (all 256 threads)
            int off = (t + 1 + psu) * 8;
            if (off > T_LEN * 8 - 8) off = T_LEN * 8 - 8;
            const float* xg = x + (size_t)(r0 + prow) * (T_LEN * 8) + off;
            xra = *(const float4*)(xg); xrb = *(const float4*)(xg + 4);
        }
        // critical: w/g accumulators last touched in prev seg4-late (1 barrier ago)
        w_a = MFMA(sA0, S1B[4], w_a);  w_b = MFMA(sA1, S1B[5], w_b);
        g_a = MFMA(sA0, G1B[2], g_a);  g_b = MFMA(sA1, G1B[3], g_b);
        {
            float wn = tanh_f(xt + w_a[0] + w_b[0]) * sigm_f(g_a[0] + g_b[0] + bias_g);
            Wl[4 * q][n] = (_Float16)wn;
        }
        // late fillers: z/r A-terms (r's A-term must be 1 barrier before seg2's critical r)
        zp_a = MFMA(sA0, ZB[4], zp_a);  zp_c = MFMA(sA1, ZB[5], zp_c);
        rp_a = MFMA(sA0, RB[4], rp_a);  rp_c = MFMA(sA1, RB[5], rp_c);
        __syncthreads();  // alpha

        // ============ seg2: r*I ============
        nW0 = ld_af(&Wl[0][0], 0); nW1 = ld_af(&Wl[0][0], 1);
        // early fillers (sA-based, fresh accumulators) cover the nW read
        hp_a = MFMA(sA0, HB[4], zero4); hp_c = MFMA(sA1, HB[5], zero4);
        ap_a = MFMA(sA0, AB[4], zero4); ap_c = MFMA(sA1, AB[5], zero4);
        if (fl16) {
            // batched phi: actions for steps t-16..t-1 from Ahist, ALL waves,
            // wave w covers sub-steps 4w..4w+3. Fragment rows m -> (su=4w+(m>>2),
            // rowidx=m&3); bitwise-identical dot to the per-step scheme.
            const _Float16* ah = &Ahist[0][0][0];
            const int hw = (4 * w + (c >> 2)) * 288 + (c & 3) * 72 + 8 * q;
            f16x8 a0 = *(const f16x8*)(ah + hw);
            f16x8 a1 = *(const f16x8*)(ah + hw + 32);
            f32x4 act = MFMA(a0, phiB[0], zero4);
            act = MFMA(a1, phiB[1], act);
            if (c < O_DIM) {
                const int slot = (t - 16 + 4 * w + q) & 63;
#pragma unroll
                for (int rg = 0; rg < 4; ++rg)
                    actb[rg][slot][c] = act[rg] + bias_p;
            }
        }
        // critical: rp last touched seg1-late (1 barrier ago)
        rp_a = MFMA(nW0, RB[0], rp_a);  rp_c = MFMA(nW1, RB[1], rp_c);
        {
            float rv = sigm_f(rp_a[0] + rp_c[0] + bias_r);
            Rl[4 * q][n] = (_Float16)(rv * Iv);
        }
        // late fillers (nW-based): grind through beta into seg3's read window
        zp_a = MFMA(nW0, ZB[0], zp_a);  zp_c = MFMA(nW1, ZB[1], zp_c);
        hp_a = MFMA(nW0, HB[0], hp_a);  hp_c = MFMA(nW1, HB[1], hp_c);
        w_a  = MFMA(nW0, S1B[0], zero4); w_b = MFMA(nW1, S1B[1], zero4);
        if (fl64) {
            float* d = &xbig[prow][psu * 8];
            *(float4*)d = xra; *(float4*)(d + 4) = xrb;
        }
        __syncthreads();  // beta

        // ============ seg3: I_new ============
        f16x8 hR0 = ld_af(&Rl[0][0], 0), hR1 = ld_af(&Rl[0][0], 1);
        const float* xs = &xbig[q][(t & 63) * 8];
        float4 qa = *(const float4*)xs;
        float4 qb = *(const float4*)(xs + 4);
        // early fillers (nW-based) + VALU cover the hR read
        ap_a = MFMA(nW0, AB[0], ap_a);  ap_c = MFMA(nW1, AB[1], ap_c);
        float zv = sigm_f(zp_a[0] + zp_c[0] + bias_z);
        float xtn;
        {
            float d = bias_e;
            d = __builtin_fmaf(qa.x, We[0], d); d = __builtin_fmaf(qa.y, We[1], d);
            d = __builtin_fmaf(qa.z, We[2], d); d = __builtin_fmaf(qa.w, We[3], d);
            d = __builtin_fmaf(qb.x, We[4], d); d = __builtin_fmaf(qb.y, We[5], d);
            d = __builtin_fmaf(qb.z, We[6], d); d = __builtin_fmaf(qb.w, We[7], d);
            xtn = tanh_f(d);
        }
        if (fl64) {  // uniform 64-step action flush (reads last seg's actb after beta)
            float4 av = *(const float4*)(&actb[frow][fs][0]);
            *(float4*)(out + (size_t)(r0 + frow) * (T_LEN * O_DIM) + (t - 64 + fs) * 4) = av;
        }
        // critical: hp last touched seg2-late (1 barrier ago)
        hp_a = MFMA(hR0, HB[2], hp_a);  hp_c = MFMA(hR1, HB[3], hp_c);
        {
            float hv = tanh_f(hp_a[0] + hp_c[0] + bias_h);
            Iv = __builtin_fmaf(zv, hv - Iv, Iv);
            Il[4 * q][n] = (_Float16)Iv;
        }
        // late fillers (nW-based, fresh): grind through gamma into seg4's read window
        ag_a = MFMA(nW0, AGB[0], zero4); ag_c = MFMA(nW1, AGB[1], zero4);
        __syncthreads();  // gamma

        // ============ seg4: A_new ============
        f16x8 nI0 = ld_af(&Il[0][0], 0), nI1 = ld_af(&Il[0][0], 1);
        // critical: ap last touched seg3-early, ag seg3-late (completed by now)
        ap_a = MFMA(nI0, AB[2], ap_a);  ap_c = MFMA(nI1, AB[3], ap_c);
        ag_a = MFMA(nI0, AGB[2], ag_a); ag_c = MFMA(nI1, AGB[3], ag_c);
        {
            float av = tanh_f(ap_a[0] + ap_c[0]) * sigm_f(ag_a[0] + ag_c[0] + bias_ag);
            Al[4 * q][n] = (_Float16)av;
            Ahist[t & 15][q][n] = (_Float16)av;   // append to phi history (same cvt)
        }
        // late fillers (nI-based): next step's W/Wg/z/r I-terms; grind through delta
        // into seg1's read window
        w_a = MFMA(nI0, S1B[2], w_a);   w_b = MFMA(nI1, S1B[3], w_b);
        g_a = MFMA(nI0, G1B[0], zero4); g_b = MFMA(nI1, G1B[1], zero4);
        zp_a = MFMA(nI0, ZB[2], zero4); zp_c = MFMA(nI1, ZB[3], zero4);
        rp_a = MFMA(nI0, RB[2], zero4); rp_c = MFMA(nI1, RB[3], zero4);
        xt = xtn;
        __syncthreads();  // delta
    }

    // epilogue: final phi batch (steps 496..511) + final flush (448..511)
    {
        const _Float16* ah = &Ahist[0][0][0];
        const int hw = (4 * w + (c >> 2)) * 288 + (c & 3) * 72 + 8 * q;
        f16x8 a0 = *(const f16x8*)(ah + hw);
        f16x8 a1 = *(const f16x8*)(ah + hw + 32);
        f32x4 act = MFMA(a0, phiB[0], zero4);
        act = MFMA(a1, phiB[1], act);
        if (c < O_DIM) {
            const int slot = 48 + 4 * w + q;   // (512-16+4w+q)&63
#pragma unroll
            for (int rg = 0; rg < 4; ++rg)
                actb[rg][slot][c] = act[rg] + bias_p;
        }
        __syncthreads();
        {
            float4 av = *(const float4*)(&actb[frow][fs][0]);
            *(float4*)(out + (size_t)(r0 + frow) * (T_LEN * O_DIM) + (448 + fs) * 4) = av;
        }
    }
}

extern "C" void kernel_launch(void* const* d_in, const int* in_sizes, int n_in,
                              void* d_out, int out_size, void* d_ws, size_t ws_size,
                              hipStream_t stream) {
    ANIMAZeroExact_86887188398421_kernel<<<dim3(256), dim3(256), 0, stream>>>(
        (const float*)d_in[0],
        (const float*)d_in[1],  (const float*)d_in[2],
        (const float*)d_in[3],  (const float*)d_in[4],  (const float*)d_in[5],
        (const float*)d_in[6],  (const float*)d_in[7],
        (const float*)d_in[8],  (const float*)d_in[9],
        (const float*)d_in[10], (const float*)d_in[11],
        (const float*)d_in[12], (const float*)d_in[13],
        (const float*)d_in[14], (const float*)d_in[15], (const float*)d_in[16],
        (const float*)d_in[17], (const float*)d_in[18],
        (const float*)d_in[19], (const float*)d_in[20],
        (float*)d_out);
}